// Round 1
// baseline (979.270 us; speedup 1.0000x reference)
//
#include <hip/hip_runtime.h>
#include <hip/hip_bf16.h>

// GPT-2 attention block, fp32 baseline.
// B=2 S=2048 D=768 H=12 hd=64. 3 kernels: QKV GEMM -> flash attn -> proj GEMM.

constexpr int B_  = 2;
constexpr int S_  = 2048;
constexpr int D_  = 768;
constexpr int H_  = 12;
constexpr int HD_ = 64;
constexpr int N3D = 3 * D_;   // 2304
constexpr int M_  = B_ * S_;  // 4096

// ---------------------------------------------------------------------------
// Generic SGEMM: C[M,N] = A[M,K] @ W[K,N] + bias[N], all row-major fp32.
// BM=128 BN=64 BK=16, 256 threads, 8x4 micro-tile.
// ---------------------------------------------------------------------------
__global__ __launch_bounds__(256)
void sgemm_bias(const float* __restrict__ A, const float* __restrict__ W,
                const float* __restrict__ bias, float* __restrict__ C,
                int M, int N, int K)
{
    constexpr int BM = 128, BN = 64, BK = 16;
    __shared__ float sA[BK][BM + 4];  // transposed A tile; +4 pad: stride 132 -> banks (4k+row)%32
    __shared__ float sB[BK][BN];      // row-major W tile; b128 reads are 2-way aliased (free)

    const int t  = threadIdx.x;
    const int tx = t & 15;            // 0..15 -> N
    const int ty = t >> 4;            // 0..15 -> M
    const int m0 = blockIdx.y * BM;
    const int n0 = blockIdx.x * BN;

    float acc[8][4];
#pragma unroll
    for (int i = 0; i < 8; ++i)
#pragma unroll
        for (int j = 0; j < 4; ++j) acc[i][j] = 0.f;

    // staging: A tile 128x16 = 2048 floats -> 2 float4/thread along K
    const int arow = t >> 1;          // 0..127
    const int akb  = (t & 1) * 8;     // 0 or 8
    // B tile 16x64 = 1024 floats -> 1 float4/thread
    const int bkr  = t >> 4;          // 0..15
    const int bcol = (t & 15) * 4;

    for (int k0 = 0; k0 < K; k0 += BK) {
        const float* Ap = A + (size_t)(m0 + arow) * K + k0 + akb;
        const float4 a0 = *(const float4*)Ap;
        const float4 a1 = *(const float4*)(Ap + 4);
        const float4 b0 = *(const float4*)(W + (size_t)(k0 + bkr) * N + n0 + bcol);

        __syncthreads();  // previous tile fully consumed before overwrite
        sA[akb + 0][arow] = a0.x; sA[akb + 1][arow] = a0.y;
        sA[akb + 2][arow] = a0.z; sA[akb + 3][arow] = a0.w;
        sA[akb + 4][arow] = a1.x; sA[akb + 5][arow] = a1.y;
        sA[akb + 6][arow] = a1.z; sA[akb + 7][arow] = a1.w;
        *(float4*)&sB[bkr][bcol] = b0;
        __syncthreads();

#pragma unroll
        for (int k = 0; k < BK; ++k) {
            const float4 x0 = *(const float4*)&sA[k][ty * 8];
            const float4 x1 = *(const float4*)&sA[k][ty * 8 + 4];
            const float4 y  = *(const float4*)&sB[k][tx * 4];
            const float xs[8] = {x0.x, x0.y, x0.z, x0.w, x1.x, x1.y, x1.z, x1.w};
            const float ys[4] = {y.x, y.y, y.z, y.w};
#pragma unroll
            for (int i = 0; i < 8; ++i)
#pragma unroll
                for (int j = 0; j < 4; ++j) acc[i][j] += xs[i] * ys[j];
        }
    }

    const float4 bb = *(const float4*)&bias[n0 + tx * 4];
#pragma unroll
    for (int i = 0; i < 8; ++i) {
        const int row = m0 + ty * 8 + i;
        float4 o;
        o.x = acc[i][0] + bb.x; o.y = acc[i][1] + bb.y;
        o.z = acc[i][2] + bb.z; o.w = acc[i][3] + bb.w;
        *(float4*)&C[(size_t)row * N + n0 + tx * 4] = o;
    }
}

// ---------------------------------------------------------------------------
// Flash attention (causal), fp32. One block = one (b, h, 64-row q-tile).
// qkv: [B, S, 2304] (q | k | v each D wide, head h at cols h*64..h*64+63)
// out: [B, S, 768]  merged heads
// Threads: 256 = (tx 0..15 -> cols/dims, ty 0..15 -> rows).
// Thread owns rows {ty+16rr}, score cols {tx+16cc}, O dims {tx*4+dd}.
// Row group = 16 consecutive lanes (same ty) -> shfl_xor softmax reduce,
// sP stays intra-wave (no extra barrier).
// ---------------------------------------------------------------------------
__global__ __launch_bounds__(256)
void flash_attn(const float* __restrict__ qkv, float* __restrict__ out)
{
    const int qt = blockIdx.x;   // 0..31
    const int h  = blockIdx.y;   // 0..11
    const int b  = blockIdx.z;   // 0..1

    __shared__ float sQ[64][68];
    __shared__ float sK[64][68];
    __shared__ float sV[64][68];
    __shared__ float sP[64][68];

    const int t  = threadIdx.x;
    const int tx = t & 15;
    const int ty = t >> 4;

    // ---- stage Q (once) ----
    {
        const int row   = t >> 2;
        const int dbase = (t & 3) * 16;
        const float* src = qkv + (size_t)(b * S_ + qt * 64 + row) * N3D + h * HD_ + dbase;
#pragma unroll
        for (int u = 0; u < 4; ++u)
            *(float4*)&sQ[row][dbase + 4 * u] = *(const float4*)(src + 4 * u);
    }

    float m[4], l[4], o[4][4];
#pragma unroll
    for (int rr = 0; rr < 4; ++rr) {
        m[rr] = -1e30f; l[rr] = 0.f;
#pragma unroll
        for (int dd = 0; dd < 4; ++dd) o[rr][dd] = 0.f;
    }

    for (int kt = 0; kt <= qt; ++kt) {
        // ---- stage K, V tile ----
        {
            const int row   = t >> 2;
            const int dbase = (t & 3) * 16;
            const float* srck = qkv + (size_t)(b * S_ + kt * 64 + row) * N3D + D_ + h * HD_ + dbase;
            float4 kv[4], vv[4];
#pragma unroll
            for (int u = 0; u < 4; ++u) {
                kv[u] = *(const float4*)(srck + 4 * u);
                vv[u] = *(const float4*)(srck + D_ + 4 * u);
            }
            __syncthreads();  // previous tile's sK/sV reads done (also covers sQ on first iter)
#pragma unroll
            for (int u = 0; u < 4; ++u) {
                *(float4*)&sK[row][dbase + 4 * u] = kv[u];
                *(float4*)&sV[row][dbase + 4 * u] = vv[u];
            }
            __syncthreads();
        }

        // ---- scores: s[rr][cc] = dot64(Q[ty+16rr], K[tx+16cc]) ----
        float s[4][4];
#pragma unroll
        for (int rr = 0; rr < 4; ++rr)
#pragma unroll
            for (int cc = 0; cc < 4; ++cc) s[rr][cc] = 0.f;

        for (int kk = 0; kk < 64; kk += 4) {
            float qv[4][4], kf[4][4];
#pragma unroll
            for (int rr = 0; rr < 4; ++rr) {
                const float4 q4 = *(const float4*)&sQ[ty + 16 * rr][kk];
                qv[rr][0] = q4.x; qv[rr][1] = q4.y; qv[rr][2] = q4.z; qv[rr][3] = q4.w;
            }
#pragma unroll
            for (int cc = 0; cc < 4; ++cc) {
                const float4 k4 = *(const float4*)&sK[tx + 16 * cc][kk];
                kf[cc][0] = k4.x; kf[cc][1] = k4.y; kf[cc][2] = k4.z; kf[cc][3] = k4.w;
            }
#pragma unroll
            for (int rr = 0; rr < 4; ++rr)
#pragma unroll
                for (int cc = 0; cc < 4; ++cc)
                    s[rr][cc] += qv[rr][0] * kf[cc][0] + qv[rr][1] * kf[cc][1]
                               + qv[rr][2] * kf[cc][2] + qv[rr][3] * kf[cc][3];
        }

        // ---- scale + causal mask (reference: scale, then where(mask, s, -1e4)) ----
        const bool diag = (kt == qt);
#pragma unroll
        for (int rr = 0; rr < 4; ++rr)
#pragma unroll
            for (int cc = 0; cc < 4; ++cc) {
                float val = s[rr][cc] * 0.125f;
                if (diag) {
                    const int rowg = qt * 64 + ty + 16 * rr;
                    const int colg = kt * 64 + tx + 16 * cc;
                    if (colg > rowg) val = -10000.0f;
                }
                s[rr][cc] = val;
            }

        // ---- online softmax (per row rr; reduce over the 16 tx lanes) ----
#pragma unroll
        for (int rr = 0; rr < 4; ++rr) {
            float rmax = fmaxf(fmaxf(s[rr][0], s[rr][1]), fmaxf(s[rr][2], s[rr][3]));
#pragma unroll
            for (int msk = 1; msk < 16; msk <<= 1)
                rmax = fmaxf(rmax, __shfl_xor(rmax, msk));
            const float nm    = fmaxf(m[rr], rmax);
            const float scale = expf(m[rr] - nm);
            float psum = 0.f;
#pragma unroll
            for (int cc = 0; cc < 4; ++cc) {
                const float p = expf(s[rr][cc] - nm);
                s[rr][cc] = p;
                psum += p;
            }
#pragma unroll
            for (int msk = 1; msk < 16; msk <<= 1)
                psum += __shfl_xor(psum, msk);
            l[rr] = l[rr] * scale + psum;
#pragma unroll
            for (int dd = 0; dd < 4; ++dd) o[rr][dd] *= scale;
            m[rr] = nm;
            // publish p to the row group (intra-wave: same 16 lanes write & read)
#pragma unroll
            for (int cc = 0; cc < 4; ++cc)
                sP[ty + 16 * rr][tx + 16 * cc] = s[rr][cc];
        }

        // ---- PV: o[rr][dd] += sum_j P[row][j] * V[j][tx*4+dd] ----
        for (int j = 0; j < 64; j += 4) {
            float vv[4][4];
#pragma unroll
            for (int jj = 0; jj < 4; ++jj) {
                const float4 v4 = *(const float4*)&sV[j + jj][tx * 4];
                vv[jj][0] = v4.x; vv[jj][1] = v4.y; vv[jj][2] = v4.z; vv[jj][3] = v4.w;
            }
#pragma unroll
            for (int rr = 0; rr < 4; ++rr) {
                const float4 p4 = *(const float4*)&sP[ty + 16 * rr][j];
                const float pp[4] = {p4.x, p4.y, p4.z, p4.w};
#pragma unroll
                for (int jj = 0; jj < 4; ++jj)
#pragma unroll
                    for (int dd = 0; dd < 4; ++dd)
                        o[rr][dd] += pp[jj] * vv[jj][dd];
            }
        }
    }

    // ---- epilogue: normalize, write merged-head layout ----
#pragma unroll
    for (int rr = 0; rr < 4; ++rr) {
        const float inv = 1.0f / l[rr];
        const int rowg = qt * 64 + ty + 16 * rr;
        float4 res;
        res.x = o[rr][0] * inv; res.y = o[rr][1] * inv;
        res.z = o[rr][2] * inv; res.w = o[rr][3] * inv;
        *(float4*)&out[(size_t)(b * S_ + rowg) * D_ + h * HD_ + tx * 4] = res;
    }
}

// ---------------------------------------------------------------------------
extern "C" void kernel_launch(void* const* d_in, const int* in_sizes, int n_in,
                              void* d_out, int out_size, void* d_ws, size_t ws_size,
                              hipStream_t stream)
{
    const float* hs    = (const float*)d_in[0];  // [B,S,D]
    const float* wqkv  = (const float*)d_in[1];  // [D,3D]
    const float* bqkv  = (const float*)d_in[2];  // [3D]
    const float* wproj = (const float*)d_in[3];  // [D,D]
    const float* bproj = (const float*)d_in[4];  // [D]
    float* out = (float*)d_out;                  // [B,S,D]

    float* qkv  = (float*)d_ws;                  // [M, 3D] = 37.7 MB
    float* attn = qkv + (size_t)M_ * N3D;        // [M, D]  = 12.6 MB

    // 1) QKV projection
    sgemm_bias<<<dim3(N3D / 64, M_ / 128), 256, 0, stream>>>(hs, wqkv, bqkv, qkv, M_, N3D, D_);
    // 2) causal flash attention, merged-head output
    flash_attn<<<dim3(S_ / 64, H_, B_), 256, 0, stream>>>(qkv, attn);
    // 3) output projection
    sgemm_bias<<<dim3(D_ / 64, M_ / 128), 256, 0, stream>>>(attn, wproj, bproj, out, M_, D_, D_);
}

// Round 2
// 253.878 us; speedup vs baseline: 3.8573x; 3.8573x over previous
//
#include <hip/hip_runtime.h>
#include <stdint.h>

// GPT-2 attention block, bf16 MFMA version.
// B=2 S=2048 D=768 H=12 hd=64.
// prep (cvt + 2 transposes) -> QKV GEMM (bf16 out) -> flash attn (MFMA) -> proj GEMM (fp32 out)

constexpr int B_  = 2;
constexpr int S_  = 2048;
constexpr int D_  = 768;
constexpr int N3D = 3 * D_;   // 2304
constexpr int M_  = B_ * S_;  // 4096

typedef __bf16 bv8 __attribute__((ext_vector_type(8)));
typedef float  fv4 __attribute__((ext_vector_type(4)));
typedef unsigned short uv4 __attribute__((ext_vector_type(4)));
typedef unsigned short uv8 __attribute__((ext_vector_type(8)));

__device__ inline unsigned short f2bf(float x) {
    union { float f; unsigned int u; } v; v.f = x;
    unsigned int r = v.u + 0x7FFFu + ((v.u >> 16) & 1u);
    return (unsigned short)(r >> 16);
}

__device__ inline fv4 mfma16(bv8 a, bv8 b, fv4 c) {
    return __builtin_amdgcn_mfma_f32_16x16x32_bf16(a, b, c, 0, 0, 0);
}

// async global->LDS, 16B per lane, LDS dest = wave-uniform base + lane*16
#define GLOAD_LDS16(g, l)                                                        \
    __builtin_amdgcn_global_load_lds(                                            \
        (__attribute__((address_space(1))) void*)(g),                            \
        (__attribute__((address_space(3))) void*)(l), 16, 0, 0)

// ---------------------------------------------------------------------------
// fp32 -> bf16 elementwise (8 elems/thread)
// ---------------------------------------------------------------------------
__global__ __launch_bounds__(256)
void cvt_f32_bf16(const float* __restrict__ in, unsigned short* __restrict__ out)
{
    const size_t i = ((size_t)blockIdx.x * 256 + threadIdx.x) * 8;
    const float4 a = *(const float4*)&in[i];
    const float4 b = *(const float4*)&in[i + 4];
    uv8 o;
    o[0] = f2bf(a.x); o[1] = f2bf(a.y); o[2] = f2bf(a.z); o[3] = f2bf(a.w);
    o[4] = f2bf(b.x); o[5] = f2bf(b.y); o[6] = f2bf(b.z); o[7] = f2bf(b.w);
    *(uv8*)&out[i] = o;
}

// ---------------------------------------------------------------------------
// W [K][N] fp32 -> WT [N][K] bf16, 32x32 tiles
// grid = (N/32, K/32)
// ---------------------------------------------------------------------------
__global__ __launch_bounds__(256)
void transpose_cvt(const float* __restrict__ W, unsigned short* __restrict__ WT,
                   int K, int N)
{
    __shared__ float tl[32][33];
    const int n0 = blockIdx.x * 32, k0 = blockIdx.y * 32;
    const int t = threadIdx.x;
    {
        const int r = t >> 3, c = (t & 7) * 4;
        const float4 v = *(const float4*)&W[(size_t)(k0 + r) * N + n0 + c];
        tl[r][c + 0] = v.x; tl[r][c + 1] = v.y; tl[r][c + 2] = v.z; tl[r][c + 3] = v.w;
    }
    __syncthreads();
    {
        const int rn = t >> 3, ck = (t & 7) * 4;
        uv4 o;
        o[0] = f2bf(tl[ck + 0][rn]); o[1] = f2bf(tl[ck + 1][rn]);
        o[2] = f2bf(tl[ck + 2][rn]); o[3] = f2bf(tl[ck + 3][rn]);
        *(uv4*)&WT[(size_t)(n0 + rn) * K + k0 + ck] = o;
    }
}

// ---------------------------------------------------------------------------
// bf16 MFMA GEMM: C[M,N] = A[M,K] @ BT[N,K]^T + bias.
// 128x128 tile, BK=32, 4 waves (2x2 of 64x64), 16x16x32 MFMA.
// LDS: [128 rows][32 k] bf16 per operand, 16B-chunk XOR swizzle c^=((row>>1)&3)
// staged via global_load_lds with pre-swizzled global source (rule #21).
// ---------------------------------------------------------------------------
template<bool OUT_BF16>
__global__ __launch_bounds__(256)
void gemm_bf16(const unsigned short* __restrict__ A, const unsigned short* __restrict__ BT,
               const float* __restrict__ bias, void* __restrict__ Cv,
               int M, int N, int K)
{
    __shared__ unsigned short sA[128 * 32];
    __shared__ unsigned short sB[128 * 32];
    const int t = threadIdx.x, w = t >> 6, lane = t & 63;
    const int l15 = lane & 15, l4 = lane >> 4;
    const int m0 = blockIdx.y * 128, n0 = blockIdx.x * 128;
    const int wr = w >> 1, wc = w & 1;

    fv4 acc[4][4];
#pragma unroll
    for (int i = 0; i < 4; ++i)
#pragma unroll
        for (int j = 0; j < 4; ++j) acc[i][j] = fv4{0.f, 0.f, 0.f, 0.f};

    // staging lane constants: pass p in {w, w+4}; chunk L=p*64+lane
    const int r0 = w * 16 + (lane >> 2);
    const int c0 = (lane & 3) ^ ((r0 >> 1) & 3);
    const int r1 = (w + 4) * 16 + (lane >> 2);
    const int c1 = (lane & 3) ^ ((r1 >> 1) & 3);

    for (int k0 = 0; k0 < K; k0 += 32) {
        __syncthreads();
        GLOAD_LDS16(A  + (size_t)(m0 + r0) * K + k0 + c0 * 8, sA + w * 512);
        GLOAD_LDS16(A  + (size_t)(m0 + r1) * K + k0 + c1 * 8, sA + (w + 4) * 512);
        GLOAD_LDS16(BT + (size_t)(n0 + r0) * K + k0 + c0 * 8, sB + w * 512);
        GLOAD_LDS16(BT + (size_t)(n0 + r1) * K + k0 + c1 * 8, sB + (w + 4) * 512);
        __syncthreads();

        bv8 af[4], bf[4];
#pragma unroll
        for (int i = 0; i < 4; ++i) {
            const int r = wr * 64 + i * 16 + l15;
            const int c = l4 ^ ((r >> 1) & 3);
            af[i] = *(const bv8*)&sA[r * 32 + c * 8];
        }
#pragma unroll
        for (int j = 0; j < 4; ++j) {
            const int r = wc * 64 + j * 16 + l15;
            const int c = l4 ^ ((r >> 1) & 3);
            bf[j] = *(const bv8*)&sB[r * 32 + c * 8];
        }
#pragma unroll
        for (int i = 0; i < 4; ++i)
#pragma unroll
            for (int j = 0; j < 4; ++j)
                acc[i][j] = mfma16(af[i], bf[j], acc[i][j]);
    }

    // epilogue: D layout col=lane&15, row=(lane>>4)*4+reg  [m89]
#pragma unroll
    for (int j = 0; j < 4; ++j) {
        const int col = n0 + wc * 64 + j * 16 + l15;
        const float bb = bias[col];
#pragma unroll
        for (int i = 0; i < 4; ++i) {
            const int rbase = m0 + wr * 64 + i * 16 + l4 * 4;
#pragma unroll
            for (int reg = 0; reg < 4; ++reg) {
                const float v = acc[i][j][reg] + bb;
                if (OUT_BF16)
                    ((unsigned short*)Cv)[(size_t)(rbase + reg) * N + col] = f2bf(v);
                else
                    ((float*)Cv)[(size_t)(rbase + reg) * N + col] = v;
            }
        }
    }
}

// ---------------------------------------------------------------------------
// MFMA flash attention (causal). Block = (qt 64 q-rows, head h, batch b),
// 4 waves x 16 q-rows. K LDS [kv64][d64], VT LDS [d64][kv64], P LDS per-wave
// [16][kv64]; all bf16 with 16B-chunk XOR swizzle c^=(row&7) (rows are 128B).
// qkv: bf16 [B*S][2304] (q|k|v), out: bf16 [B*S][768] merged heads.
// ---------------------------------------------------------------------------
__global__ __launch_bounds__(256)
void flash_mfma(const unsigned short* __restrict__ qkv, unsigned short* __restrict__ outb)
{
    const int qt = 31 - blockIdx.x;      // big tiles dispatch first
    const int h  = blockIdx.y, b = blockIdx.z;

    __shared__ unsigned short sK [64 * 64];
    __shared__ unsigned short sVT[64 * 64];
    __shared__ unsigned short sP [4 * 16 * 64];

    const int t = threadIdx.x, w = t >> 6, lane = t & 63;
    const int l15 = lane & 15, l4 = lane >> 4;
    const int qrow = qt * 64 + w * 16;   // wave's q-row base (global within seq)

    // Q fragments (A layout: row=lane&15, k=(lane>>4)*8+j)
    bv8 qa[2];
    {
        const size_t qoff = (size_t)(b * S_ + qrow + l15) * N3D + h * 64 + l4 * 8;
        qa[0] = *(const bv8*)&qkv[qoff];
        qa[1] = *(const bv8*)&qkv[qoff + 32];
    }

    fv4 o[4];
    float m[4], l[4];
#pragma unroll
    for (int j = 0; j < 4; ++j) o[j] = fv4{0.f, 0.f, 0.f, 0.f};
#pragma unroll
    for (int r = 0; r < 4; ++r) { m[r] = -1e30f; l[r] = 0.f; }

    // staging lane constants
    const int kvV = t & 63, dgV = (t >> 6) * 16;              // V transpose stage
    const int rK0 = (2 * w) * 8 + (lane >> 3);                // K gload_lds pass 2w
    const int cK0 = (lane & 7) ^ (rK0 & 7);
    const int rK1 = (2 * w + 1) * 8 + (lane >> 3);            // pass 2w+1
    const int cK1 = (lane & 7) ^ (rK1 & 7);
    const int pw = w * 1024;                                   // per-wave P region

    for (int kt = 0; kt <= qt; ++kt) {
        const size_t kb = (size_t)(b * S_ + kt * 64);
        __syncthreads();  // prev tile's sK/sVT/sP reads complete
        GLOAD_LDS16(qkv + (kb + rK0) * N3D + D_ + h * 64 + cK0 * 8, sK + (2 * w) * 512);
        GLOAD_LDS16(qkv + (kb + rK1) * N3D + D_ + h * 64 + cK1 * 8, sK + (2 * w + 1) * 512);
        // V: reg-stage + transposed swizzled ds_write
        const uv8 v0 = *(const uv8*)&qkv[(kb + kvV) * N3D + 2 * D_ + h * 64 + dgV];
        const uv8 v1 = *(const uv8*)&qkv[(kb + kvV) * N3D + 2 * D_ + h * 64 + dgV + 8];
#pragma unroll
        for (int u = 0; u < 16; ++u) {
            const int d = dgV + u;
            const unsigned short val = (u < 8) ? v0[u] : v1[u - 8];
            sVT[d * 64 + (((kvV >> 3) ^ (d & 7)) * 8) + (kvV & 7)] = val;
        }
        __syncthreads();  // K staged (vmcnt drained by barrier) + VT visible

        // ---- S = Q K^T : 4 col-frags x 2 k-halves ----
        fv4 s[4];
#pragma unroll
        for (int j = 0; j < 4; ++j) s[j] = fv4{0.f, 0.f, 0.f, 0.f};
#pragma unroll
        for (int j = 0; j < 4; ++j) {
            const int kv = j * 16 + l15;
#pragma unroll
            for (int hh = 0; hh < 2; ++hh) {
                const int c = hh * 4 + l4;
                const bv8 kbf = *(const bv8*)&sK[kv * 64 + ((c ^ (kv & 7)) * 8)];
                s[j] = mfma16(qa[hh], kbf, s[j]);
            }
        }

        // ---- scale + causal mask (reference order: scale, then -10000) ----
        float ps[4][4];
        const bool diag = (kt == qt);
#pragma unroll
        for (int j = 0; j < 4; ++j) {
            const int colg = kt * 64 + j * 16 + l15;
#pragma unroll
            for (int reg = 0; reg < 4; ++reg) {
                float v = s[j][reg] * 0.125f;
                if (diag && colg > qrow + l4 * 4 + reg) v = -10000.0f;
                ps[j][reg] = v;
            }
        }

        // ---- online softmax per row (reduce over 16-lane col group) ----
#pragma unroll
        for (int reg = 0; reg < 4; ++reg) {
            float rmax = fmaxf(fmaxf(ps[0][reg], ps[1][reg]), fmaxf(ps[2][reg], ps[3][reg]));
#pragma unroll
            for (int msk = 1; msk < 16; msk <<= 1)
                rmax = fmaxf(rmax, __shfl_xor(rmax, msk));
            const float nm = fmaxf(m[reg], rmax);
            const float sc = __expf(m[reg] - nm);
            float psum = 0.f;
#pragma unroll
            for (int j = 0; j < 4; ++j) {
                const float p = __expf(ps[j][reg] - nm);
                ps[j][reg] = p;
                psum += p;
            }
#pragma unroll
            for (int msk = 1; msk < 16; msk <<= 1)
                psum += __shfl_xor(psum, msk);
            l[reg] = l[reg] * sc + psum;
            m[reg] = nm;
#pragma unroll
            for (int j = 0; j < 4; ++j) o[j][reg] *= sc;
        }

        // ---- P -> LDS (bf16, swizzled; own-wave region) ----
#pragma unroll
        for (int j = 0; j < 4; ++j) {
            const int col = j * 16 + l15, cw = col >> 3;
#pragma unroll
            for (int reg = 0; reg < 4; ++reg) {
                const int r = l4 * 4 + reg;
                sP[pw + r * 64 + ((cw ^ (r & 7)) * 8) + (col & 7)] = f2bf(ps[j][reg]);
            }
        }
        __syncthreads();  // ordering safety for sP write->read

        // ---- O += P V ----
        bv8 pa[2];
#pragma unroll
        for (int hh = 0; hh < 2; ++hh) {
            const int c = hh * 4 + l4;
            pa[hh] = *(const bv8*)&sP[pw + l15 * 64 + ((c ^ (l15 & 7)) * 8)];
        }
#pragma unroll
        for (int j = 0; j < 4; ++j) {
            const int d = j * 16 + l15;
#pragma unroll
            for (int hh = 0; hh < 2; ++hh) {
                const int c = hh * 4 + l4;
                const bv8 vb = *(const bv8*)&sVT[d * 64 + ((c ^ (d & 7)) * 8)];
                o[j] = mfma16(pa[hh], vb, o[j]);
            }
        }
    }

    // ---- epilogue: normalize, bf16 merged-head write ----
#pragma unroll
    for (int reg = 0; reg < 4; ++reg) {
        const float inv = 1.0f / l[reg];
        const size_t rg = (size_t)(b * S_ + qrow + l4 * 4 + reg);
#pragma unroll
        for (int j = 0; j < 4; ++j)
            outb[rg * D_ + h * 64 + j * 16 + l15] = f2bf(o[j][reg] * inv);
    }
}

// ---------------------------------------------------------------------------
extern "C" void kernel_launch(void* const* d_in, const int* in_sizes, int n_in,
                              void* d_out, int out_size, void* d_ws, size_t ws_size,
                              hipStream_t stream)
{
    const float* hs    = (const float*)d_in[0];  // [B,S,D]
    const float* wqkv  = (const float*)d_in[1];  // [D,3D]
    const float* bqkv  = (const float*)d_in[2];  // [3D]
    const float* wproj = (const float*)d_in[3];  // [D,D]
    const float* bproj = (const float*)d_in[4];  // [D]
    float* out = (float*)d_out;                  // [B,S,D] fp32

    // workspace carve (bf16 buffers)
    unsigned short* hsb    = (unsigned short*)d_ws;                 // [4096][768]
    unsigned short* wqkvT  = hsb    + (size_t)M_ * D_;              // [2304][768]
    unsigned short* wprojT = wqkvT  + (size_t)N3D * D_;             // [768][768]
    unsigned short* qkvb   = wprojT + (size_t)D_ * D_;              // [4096][2304]
    unsigned short* attnb  = qkvb   + (size_t)M_ * N3D;             // [4096][768]

    // prep: convert/transpose to bf16
    cvt_f32_bf16<<<(M_ * D_) / (256 * 8), 256, 0, stream>>>(hs, hsb);
    transpose_cvt<<<dim3(N3D / 32, D_ / 32), 256, 0, stream>>>(wqkv, wqkvT, D_, N3D);
    transpose_cvt<<<dim3(D_ / 32, D_ / 32), 256, 0, stream>>>(wproj, wprojT, D_, D_);

    // 1) QKV projection (bf16 out)
    gemm_bf16<true><<<dim3(N3D / 128, M_ / 128), 256, 0, stream>>>(
        hsb, wqkvT, bqkv, qkvb, M_, N3D, D_);
    // 2) causal flash attention (MFMA), bf16 merged-head out
    flash_mfma<<<dim3(32, 12, 2), 256, 0, stream>>>(qkvb, attnb);
    // 3) output projection (fp32 out)
    gemm_bf16<false><<<dim3(D_ / 128, M_ / 128), 256, 0, stream>>>(
        attnb, wprojT, bproj, out, M_, D_, D_);
}

// Round 3
// 187.075 us; speedup vs baseline: 5.2346x; 1.3571x over previous
//
#include <hip/hip_runtime.h>
#include <stdint.h>

// GPT-2 attention block, bf16 MFMA, double-buffered (counted vmcnt).
// B=2 S=2048 D=768 H=12 hd=64.
// cvt + 2 weight-transposes -> QKV GEMM (writes Q,K,V^T per-head layouts)
// -> flash attn (S^T-swapped MFMA, dbuf K/V^T) -> proj GEMM (fp32 out).

constexpr int B_  = 2;
constexpr int S_  = 2048;
constexpr int D_  = 768;
constexpr int N3D = 3 * D_;   // 2304
constexpr int M_  = B_ * S_;  // 4096

typedef __bf16 bv8 __attribute__((ext_vector_type(8)));
typedef float  fv4 __attribute__((ext_vector_type(4)));
typedef unsigned short uv4 __attribute__((ext_vector_type(4)));
typedef unsigned short uv8 __attribute__((ext_vector_type(8)));

__device__ inline unsigned short f2bf(float x) {
    union { float f; unsigned int u; } v; v.f = x;
    unsigned int r = v.u + 0x7FFFu + ((v.u >> 16) & 1u);
    return (unsigned short)(r >> 16);
}

__device__ inline fv4 mfma16(bv8 a, bv8 b, fv4 c) {
    return __builtin_amdgcn_mfma_f32_16x16x32_bf16(a, b, c, 0, 0, 0);
}

#define GLOAD_LDS16(g, l)                                                        \
    __builtin_amdgcn_global_load_lds(                                            \
        (__attribute__((address_space(1))) void*)(g),                            \
        (__attribute__((address_space(3))) void*)(l), 16, 0, 0)

#define VMCNT4() asm volatile("s_waitcnt vmcnt(4)" ::: "memory")
#define VMCNT0() asm volatile("s_waitcnt vmcnt(0)" ::: "memory")
#define BAR()                                                                    \
    do { asm volatile("" ::: "memory"); __builtin_amdgcn_s_barrier();            \
         asm volatile("" ::: "memory"); } while (0)

// ---------------------------------------------------------------------------
// fp32 -> bf16 elementwise
// ---------------------------------------------------------------------------
__global__ __launch_bounds__(256)
void cvt_f32_bf16(const float* __restrict__ in, unsigned short* __restrict__ out)
{
    const size_t i = ((size_t)blockIdx.x * 256 + threadIdx.x) * 8;
    const float4 a = *(const float4*)&in[i];
    const float4 b = *(const float4*)&in[i + 4];
    uv8 o;
    o[0] = f2bf(a.x); o[1] = f2bf(a.y); o[2] = f2bf(a.z); o[3] = f2bf(a.w);
    o[4] = f2bf(b.x); o[5] = f2bf(b.y); o[6] = f2bf(b.z); o[7] = f2bf(b.w);
    *(uv8*)&out[i] = o;
}

// ---------------------------------------------------------------------------
// W [K][N] fp32 -> WT [N][K] bf16
// ---------------------------------------------------------------------------
__global__ __launch_bounds__(256)
void transpose_cvt(const float* __restrict__ W, unsigned short* __restrict__ WT,
                   int K, int N)
{
    __shared__ float tl[32][33];
    const int n0 = blockIdx.x * 32, k0 = blockIdx.y * 32;
    const int t = threadIdx.x;
    {
        const int r = t >> 3, c = (t & 7) * 4;
        const float4 v = *(const float4*)&W[(size_t)(k0 + r) * N + n0 + c];
        tl[r][c + 0] = v.x; tl[r][c + 1] = v.y; tl[r][c + 2] = v.z; tl[r][c + 3] = v.w;
    }
    __syncthreads();
    {
        const int rn = t >> 3, ck = (t & 7) * 4;
        uv4 o;
        o[0] = f2bf(tl[ck + 0][rn]); o[1] = f2bf(tl[ck + 1][rn]);
        o[2] = f2bf(tl[ck + 2][rn]); o[3] = f2bf(tl[ck + 3][rn]);
        *(uv4*)&WT[(size_t)(n0 + rn) * K + k0 + ck] = o;
    }
}

// ---------------------------------------------------------------------------
// bf16 MFMA GEMM, 128x128 tile, BK=32, double-buffered LDS, counted vmcnt.
// QKV=true : epilogue scatters into Q[bh][s][64], K[bh][s][64], VT[bh][64][s].
// QKV=false: epilogue writes fp32 row-major C.
// ---------------------------------------------------------------------------
template<bool QKV>
__global__ __launch_bounds__(256)
void gemm_bf16(const unsigned short* __restrict__ A, const unsigned short* __restrict__ BT,
               const float* __restrict__ bias, float* __restrict__ Cf,
               unsigned short* __restrict__ Qb, unsigned short* __restrict__ Kb,
               unsigned short* __restrict__ VTb, int M, int N, int K)
{
    __shared__ unsigned short sA[2][128 * 32];
    __shared__ unsigned short sB[2][128 * 32];
    const int t = threadIdx.x, w = t >> 6, lane = t & 63;
    const int l15 = lane & 15, l4 = lane >> 4;
    const int m0 = blockIdx.y * 128, n0 = blockIdx.x * 128;
    const int wr = w >> 1, wc = w & 1;

    fv4 acc[4][4];
#pragma unroll
    for (int i = 0; i < 4; ++i)
#pragma unroll
        for (int j = 0; j < 4; ++j) acc[i][j] = fv4{0.f, 0.f, 0.f, 0.f};

    // staging: pass p covers chunks p*64+lane; r=p*16+(lane>>2), c'=lane&3,
    // source chunk = c' ^ ((r>>1)&3)  (involution; read side uses same XOR)
    const int r0 = w * 16 + (lane >> 2);
    const int c0 = (lane & 3) ^ ((r0 >> 1) & 3);
    const int r1 = (w + 4) * 16 + (lane >> 2);
    const int c1 = (lane & 3) ^ ((r1 >> 1) & 3);

    auto stage = [&](int buf, int k0) {
        GLOAD_LDS16(A  + (size_t)(m0 + r0) * K + k0 + c0 * 8, &sA[buf][w * 512]);
        GLOAD_LDS16(A  + (size_t)(m0 + r1) * K + k0 + c1 * 8, &sA[buf][(w + 4) * 512]);
        GLOAD_LDS16(BT + (size_t)(n0 + r0) * K + k0 + c0 * 8, &sB[buf][w * 512]);
        GLOAD_LDS16(BT + (size_t)(n0 + r1) * K + k0 + c1 * 8, &sB[buf][(w + 4) * 512]);
    };

    stage(0, 0);
    const int nt = K >> 5;
    for (int tt = 0; tt < nt; ++tt) {
        const int cur = tt & 1;
        if (tt + 1 < nt) { stage(cur ^ 1, (tt + 1) * 32); VMCNT4(); }
        else             { VMCNT0(); }
        BAR();

        bv8 af[4], bf[4];
#pragma unroll
        for (int i = 0; i < 4; ++i) {
            const int r = wr * 64 + i * 16 + l15;
            const int c = l4 ^ ((r >> 1) & 3);
            af[i] = *(const bv8*)&sA[cur][r * 32 + c * 8];
        }
#pragma unroll
        for (int j = 0; j < 4; ++j) {
            const int r = wc * 64 + j * 16 + l15;
            const int c = l4 ^ ((r >> 1) & 3);
            bf[j] = *(const bv8*)&sB[cur][r * 32 + c * 8];
        }
#pragma unroll
        for (int i = 0; i < 4; ++i)
#pragma unroll
            for (int j = 0; j < 4; ++j)
                acc[i][j] = mfma16(af[i], bf[j], acc[i][j]);
        BAR();  // all waves done with buf[cur] before next overwrite
    }

    // epilogue: D col=lane&15 (B free idx), row=(lane>>4)*4+reg (A free idx)
#pragma unroll
    for (int jf = 0; jf < 4; ++jf) {
        const int col = n0 + wc * 64 + jf * 16 + l15;
        const float bb = bias[col];
        if (QKV) {
            const int sect = col / 768;
            const int rem  = col - sect * 768;
            const int hh_  = rem >> 6, d = rem & 63;
#pragma unroll
            for (int i = 0; i < 4; ++i) {
                const int rowb = m0 + wr * 64 + i * 16 + l4 * 4;
                const size_t bh = (size_t)(rowb >> 11) * 12 + hh_;
                const int s0 = rowb & 2047;
                if (sect == 2) {
                    uv4 pk;
#pragma unroll
                    for (int reg = 0; reg < 4; ++reg) pk[reg] = f2bf(acc[i][jf][reg] + bb);
                    *(uv4*)&VTb[(bh * 64 + d) * 2048 + s0] = pk;
                } else {
                    unsigned short* dst = (sect == 0) ? Qb : Kb;
#pragma unroll
                    for (int reg = 0; reg < 4; ++reg)
                        dst[(bh * 2048 + s0 + reg) * 64 + d] = f2bf(acc[i][jf][reg] + bb);
                }
            }
        } else {
#pragma unroll
            for (int i = 0; i < 4; ++i) {
                const int rowb = m0 + wr * 64 + i * 16 + l4 * 4;
#pragma unroll
                for (int reg = 0; reg < 4; ++reg)
                    Cf[(size_t)(rowb + reg) * N + col] = acc[i][jf][reg] + bb;
            }
        }
    }
}

// ---------------------------------------------------------------------------
// Flash attention (causal), S^T-swapped MFMA, double-buffered K/V^T staging.
// Block = (qt, h, b): 64 q-rows, 4 waves x 16 q-rows. Tiles 64 kv.
// LDS tiles [64][64] bf16, 16B-chunk XOR swizzle c' = c ^ (r&7).
// S^T = mfma(A=K, B=Q): lane owns ONE q (l15), 16 kv values -> softmax state
// is 1 scalar/lane, cross-lane reduce = shfl_xor(16,32) only.
// ---------------------------------------------------------------------------
__global__ __launch_bounds__(256)
void flash_mfma(const unsigned short* __restrict__ Qb, const unsigned short* __restrict__ Kb,
                const unsigned short* __restrict__ VTb, unsigned short* __restrict__ outb)
{
    const int qt = 31 - blockIdx.x;      // big tiles first
    const int h  = blockIdx.y, b = blockIdx.z;
    const int bh = b * 12 + h;

    __shared__ unsigned short sK [2][64 * 64];
    __shared__ unsigned short sVT[2][64 * 64];
    __shared__ unsigned short sP [4][16 * 64];

    const int t = threadIdx.x, w = t >> 6, lane = t & 63;
    const int l15 = lane & 15, l4 = lane >> 4;
    const int qrow = qt * 64 + w * 16;

    // staging constants: pass p in {w, w+4}; r = p*8+(lane>>3), c' = lane&7
    const int sr0 = w * 8 + (lane >> 3), sc0 = (lane & 7) ^ (sr0 & 7);
    const int sr1 = (w + 4) * 8 + (lane >> 3), sc1 = (lane & 7) ^ (sr1 & 7);
    const unsigned short* Kbase = Kb  + (size_t)bh * 2048 * 64;
    const unsigned short* Vbase = VTb + (size_t)bh * 64 * 2048;

    auto stage = [&](int buf, int kt) {
        GLOAD_LDS16(Kbase + (size_t)(kt * 64 + sr0) * 64 + sc0 * 8, &sK[buf][w * 512]);
        GLOAD_LDS16(Kbase + (size_t)(kt * 64 + sr1) * 64 + sc1 * 8, &sK[buf][(w + 4) * 512]);
        GLOAD_LDS16(Vbase + (size_t)sr0 * 2048 + kt * 64 + sc0 * 8, &sVT[buf][w * 512]);
        GLOAD_LDS16(Vbase + (size_t)sr1 * 2048 + kt * 64 + sc1 * 8, &sVT[buf][(w + 4) * 512]);
    };

    // Q as B-fragment: col=q=l15, k=d=hh*32+l4*8+j  (contiguous 16B loads)
    bv8 qf[2];
    {
        const unsigned short* qp = Qb + ((size_t)bh * 2048 + qrow + l15) * 64 + l4 * 8;
        qf[0] = *(const bv8*)qp;
        qf[1] = *(const bv8*)(qp + 32);
    }

    fv4 o[4];
#pragma unroll
    for (int j = 0; j < 4; ++j) o[j] = fv4{0.f, 0.f, 0.f, 0.f};
    float m_ = -1e30f, l_ = 0.f;

    stage(0, 0);
    for (int kt = 0; kt <= qt; ++kt) {
        const int cur = kt & 1;
        if (kt < qt) { stage(cur ^ 1, kt + 1); VMCNT4(); }
        else         { VMCNT0(); }
        BAR();

        // ---- S^T[kv][q]: A=K frag (row=kv=l15 within frag), B=Q ----
        fv4 st[4];
#pragma unroll
        for (int jf = 0; jf < 4; ++jf) {
            st[jf] = fv4{0.f, 0.f, 0.f, 0.f};
            const int kr = jf * 16 + l15;
#pragma unroll
            for (int hh = 0; hh < 2; ++hh) {
                const bv8 ka = *(const bv8*)&sK[cur][kr * 64 + (((hh * 4 + l4) ^ (kr & 7)) * 8)];
                st[jf] = mfma16(ka, qf[hh], st[jf]);
            }
        }

        // ---- scale + causal mask (lane: q = qrow+l15, kv = kt*64+jf*16+l4*4+reg) ----
        float ps[16];
        const bool dtile = (kt == qt);
        const int qg = qrow + l15;
#pragma unroll
        for (int jf = 0; jf < 4; ++jf)
#pragma unroll
            for (int reg = 0; reg < 4; ++reg) {
                float v = st[jf][reg] * 0.125f;
                if (dtile && (kt * 64 + jf * 16 + l4 * 4 + reg) > qg) v = -10000.0f;
                ps[jf * 4 + reg] = v;
            }

        // ---- online softmax: 1 q per lane; reduce over l4 copies (xor 16,32) ----
        float rmax = ps[0];
#pragma unroll
        for (int u = 1; u < 16; ++u) rmax = fmaxf(rmax, ps[u]);
        rmax = fmaxf(rmax, __shfl_xor(rmax, 16));
        rmax = fmaxf(rmax, __shfl_xor(rmax, 32));
        const float nm = fmaxf(m_, rmax);
        const float sc = __expf(m_ - nm);
        float psum = 0.f;
#pragma unroll
        for (int u = 0; u < 16; ++u) {
            const float p = __expf(ps[u] - nm);
            ps[u] = p;
            psum += p;
        }
        psum += __shfl_xor(psum, 16);
        psum += __shfl_xor(psum, 32);
        l_ = l_ * sc + psum;
        m_ = nm;

        // O rescale: O rows are q=l4*4+reg -> gather sc from lane l4*4+reg
        float scq[4];
#pragma unroll
        for (int reg = 0; reg < 4; ++reg) scq[reg] = __shfl(sc, l4 * 4 + reg);
#pragma unroll
        for (int jf = 0; jf < 4; ++jf)
#pragma unroll
            for (int reg = 0; reg < 4; ++reg) o[jf][reg] *= scq[reg];

        // ---- P -> LDS (packed b64 per frag; swizzled; own-wave region) ----
#pragma unroll
        for (int jf = 0; jf < 4; ++jf) {
            uv4 pk;
#pragma unroll
            for (int reg = 0; reg < 4; ++reg) pk[reg] = f2bf(ps[jf * 4 + reg]);
            const int chunk = jf * 2 + (l4 >> 1);
            *(uv4*)&sP[w][l15 * 64 + ((chunk ^ (l15 & 7)) * 8) + (l4 & 1) * 4] = pk;
        }

        // ---- O += P V : A=P (row=q=l15), B=V^T (col=d=l15) ----
        bv8 pa[2];
#pragma unroll
        for (int hh = 0; hh < 2; ++hh)
            pa[hh] = *(const bv8*)&sP[w][l15 * 64 + (((hh * 4 + l4) ^ (l15 & 7)) * 8)];
#pragma unroll
        for (int jf = 0; jf < 4; ++jf) {
            const int dr = jf * 16 + l15;
#pragma unroll
            for (int hh = 0; hh < 2; ++hh) {
                const bv8 vb = *(const bv8*)&sVT[cur][dr * 64 + (((hh * 4 + l4) ^ (dr & 7)) * 8)];
                o[jf] = mfma16(pa[hh], vb, o[jf]);
            }
        }
        BAR();  // all waves done reading buf[cur] before next iter overwrites
    }

    // ---- epilogue ----
    const float inv = 1.0f / l_;
    float invq[4];
#pragma unroll
    for (int reg = 0; reg < 4; ++reg) invq[reg] = __shfl(inv, l4 * 4 + reg);
#pragma unroll
    for (int jf = 0; jf < 4; ++jf)
#pragma unroll
        for (int reg = 0; reg < 4; ++reg)
            outb[(size_t)(b * S_ + qrow + l4 * 4 + reg) * D_ + h * 64 + jf * 16 + l15] =
                f2bf(o[jf][reg] * invq[reg]);
}

// ---------------------------------------------------------------------------
extern "C" void kernel_launch(void* const* d_in, const int* in_sizes, int n_in,
                              void* d_out, int out_size, void* d_ws, size_t ws_size,
                              hipStream_t stream)
{
    const float* hs    = (const float*)d_in[0];
    const float* wqkv  = (const float*)d_in[1];
    const float* bqkv  = (const float*)d_in[2];
    const float* wproj = (const float*)d_in[3];
    const float* bproj = (const float*)d_in[4];
    float* out = (float*)d_out;

    unsigned short* hsb    = (unsigned short*)d_ws;                 // [4096][768]
    unsigned short* wqkvT  = hsb    + (size_t)M_ * D_;              // [2304][768]
    unsigned short* wprojT = wqkvT  + (size_t)N3D * D_;             // [768][768]
    unsigned short* Qb     = wprojT + (size_t)D_ * D_;              // [24][2048][64]
    unsigned short* Kb     = Qb     + (size_t)24 * 2048 * 64;
    unsigned short* VTb    = Kb     + (size_t)24 * 2048 * 64;       // [24][64][2048]
    unsigned short* attnb  = VTb    + (size_t)24 * 2048 * 64;       // [4096][768]

    cvt_f32_bf16<<<(M_ * D_) / (256 * 8), 256, 0, stream>>>(hs, hsb);
    transpose_cvt<<<dim3(N3D / 32, D_ / 32), 256, 0, stream>>>(wqkv, wqkvT, D_, N3D);
    transpose_cvt<<<dim3(D_ / 32, D_ / 32), 256, 0, stream>>>(wproj, wprojT, D_, D_);

    gemm_bf16<true><<<dim3(N3D / 128, M_ / 128), 256, 0, stream>>>(
        hsb, wqkvT, bqkv, nullptr, Qb, Kb, VTb, M_, N3D, D_);
    flash_mfma<<<dim3(32, 12, 2), 256, 0, stream>>>(Qb, Kb, VTb, attnb);
    gemm_bf16<false><<<dim3(D_ / 128, M_ / 128), 256, 0, stream>>>(
        attnb, wprojT, bproj, out, nullptr, nullptr, nullptr, M_, D_, D_);
}

// Round 4
// 177.662 us; speedup vs baseline: 5.5120x; 1.0530x over previous
//
#include <hip/hip_runtime.h>
#include <stdint.h>

// GPT-2 attention block, bf16 MFMA, double-buffered, work-queue balanced flash.
// B=2 S=2048 D=768 H=12 hd=64.
// cvt(+queue reset) + 2 weight-transposes -> QKV GEMM (writes Q*scale, K, V^T)
// -> flash attn (S^T-swapped MFMA, exp2 softmax, defer-max, atomic queue)
// -> proj GEMM (fp32 out).

constexpr int B_  = 2;
constexpr int S_  = 2048;
constexpr int D_  = 768;
constexpr int N3D = 3 * D_;   // 2304
constexpr int M_  = B_ * S_;  // 4096
constexpr int NTILE = 32 * 24;            // q-tiles total (qt x bh)
// Q pre-scale: 1/sqrt(64) * log2(e)  (softmax runs in exp2 domain)
#define QSCALE 0.1803368801111f
#define MASKB  (-14426.950408889634f)      // -10000 * log2(e)
#define DEFER_THR 11.5f                    // 8 nats in log2 units

typedef __bf16 bv8 __attribute__((ext_vector_type(8)));
typedef float  fv4 __attribute__((ext_vector_type(4)));
typedef unsigned short uv4 __attribute__((ext_vector_type(4)));
typedef unsigned short uv8 __attribute__((ext_vector_type(8)));

__device__ inline unsigned short f2bf(float x) {
    __bf16 b = (__bf16)x;                  // native v_cvt (pk-fused by compiler)
    return __builtin_bit_cast(unsigned short, b);
}

__device__ inline fv4 mfma16(bv8 a, bv8 b, fv4 c) {
    return __builtin_amdgcn_mfma_f32_16x16x32_bf16(a, b, c, 0, 0, 0);
}

#define GLOAD_LDS16(g, l)                                                        \
    __builtin_amdgcn_global_load_lds(                                            \
        (__attribute__((address_space(1))) void*)(g),                            \
        (__attribute__((address_space(3))) void*)(l), 16, 0, 0)

#define VMCNT4() asm volatile("s_waitcnt vmcnt(4)" ::: "memory")
#define VMCNT0() asm volatile("s_waitcnt vmcnt(0)" ::: "memory")
#define BAR()                                                                    \
    do { asm volatile("" ::: "memory"); __builtin_amdgcn_s_barrier();            \
         asm volatile("" ::: "memory"); } while (0)

// ---------------------------------------------------------------------------
// fp32 -> bf16 elementwise; block 0 also resets the flash work-queue counter.
// ---------------------------------------------------------------------------
__global__ __launch_bounds__(256)
void cvt_f32_bf16(const float* __restrict__ in, unsigned short* __restrict__ out,
                  int* __restrict__ cnt)
{
    if (blockIdx.x == 0 && threadIdx.x == 0) *cnt = 0;
    const size_t i = ((size_t)blockIdx.x * 256 + threadIdx.x) * 8;
    const float4 a = *(const float4*)&in[i];
    const float4 b = *(const float4*)&in[i + 4];
    uv8 o;
    o[0] = f2bf(a.x); o[1] = f2bf(a.y); o[2] = f2bf(a.z); o[3] = f2bf(a.w);
    o[4] = f2bf(b.x); o[5] = f2bf(b.y); o[6] = f2bf(b.z); o[7] = f2bf(b.w);
    *(uv8*)&out[i] = o;
}

// ---------------------------------------------------------------------------
// W [K][N] fp32 -> WT [N][K] bf16
// ---------------------------------------------------------------------------
__global__ __launch_bounds__(256)
void transpose_cvt(const float* __restrict__ W, unsigned short* __restrict__ WT,
                   int K, int N)
{
    __shared__ float tl[32][33];
    const int n0 = blockIdx.x * 32, k0 = blockIdx.y * 32;
    const int t = threadIdx.x;
    {
        const int r = t >> 3, c = (t & 7) * 4;
        const float4 v = *(const float4*)&W[(size_t)(k0 + r) * N + n0 + c];
        tl[r][c + 0] = v.x; tl[r][c + 1] = v.y; tl[r][c + 2] = v.z; tl[r][c + 3] = v.w;
    }
    __syncthreads();
    {
        const int rn = t >> 3, ck = (t & 7) * 4;
        uv4 o;
        o[0] = f2bf(tl[ck + 0][rn]); o[1] = f2bf(tl[ck + 1][rn]);
        o[2] = f2bf(tl[ck + 2][rn]); o[3] = f2bf(tl[ck + 3][rn]);
        *(uv4*)&WT[(size_t)(n0 + rn) * K + k0 + ck] = o;
    }
}

// ---------------------------------------------------------------------------
// bf16 MFMA GEMM, 128x128 tile, BK=32, double-buffered LDS, counted vmcnt.
// QKV=true : epilogue scatters Q*QSCALE, K, V^T into per-head layouts.
// QKV=false: fp32 row-major C.
// ---------------------------------------------------------------------------
template<bool QKV>
__global__ __launch_bounds__(256)
void gemm_bf16(const unsigned short* __restrict__ A, const unsigned short* __restrict__ BT,
               const float* __restrict__ bias, float* __restrict__ Cf,
               unsigned short* __restrict__ Qb, unsigned short* __restrict__ Kb,
               unsigned short* __restrict__ VTb, int M, int N, int K)
{
    __shared__ unsigned short sA[2][128 * 32];
    __shared__ unsigned short sB[2][128 * 32];
    const int t = threadIdx.x, w = t >> 6, lane = t & 63;
    const int l15 = lane & 15, l4 = lane >> 4;
    const int m0 = blockIdx.y * 128, n0 = blockIdx.x * 128;
    const int wr = w >> 1, wc = w & 1;

    fv4 acc[4][4];
#pragma unroll
    for (int i = 0; i < 4; ++i)
#pragma unroll
        for (int j = 0; j < 4; ++j) acc[i][j] = fv4{0.f, 0.f, 0.f, 0.f};

    const int r0 = w * 16 + (lane >> 2);
    const int c0 = (lane & 3) ^ ((r0 >> 1) & 3);
    const int r1 = (w + 4) * 16 + (lane >> 2);
    const int c1 = (lane & 3) ^ ((r1 >> 1) & 3);

    auto stage = [&](int buf, int k0) {
        GLOAD_LDS16(A  + (size_t)(m0 + r0) * K + k0 + c0 * 8, &sA[buf][w * 512]);
        GLOAD_LDS16(A  + (size_t)(m0 + r1) * K + k0 + c1 * 8, &sA[buf][(w + 4) * 512]);
        GLOAD_LDS16(BT + (size_t)(n0 + r0) * K + k0 + c0 * 8, &sB[buf][w * 512]);
        GLOAD_LDS16(BT + (size_t)(n0 + r1) * K + k0 + c1 * 8, &sB[buf][(w + 4) * 512]);
    };

    stage(0, 0);
    const int nt = K >> 5;
    for (int tt = 0; tt < nt; ++tt) {
        const int cur = tt & 1;
        if (tt + 1 < nt) { stage(cur ^ 1, (tt + 1) * 32); VMCNT4(); }
        else             { VMCNT0(); }
        BAR();

        bv8 af[4], bf[4];
#pragma unroll
        for (int i = 0; i < 4; ++i) {
            const int r = wr * 64 + i * 16 + l15;
            const int c = l4 ^ ((r >> 1) & 3);
            af[i] = *(const bv8*)&sA[cur][r * 32 + c * 8];
        }
#pragma unroll
        for (int j = 0; j < 4; ++j) {
            const int r = wc * 64 + j * 16 + l15;
            const int c = l4 ^ ((r >> 1) & 3);
            bf[j] = *(const bv8*)&sB[cur][r * 32 + c * 8];
        }
#pragma unroll
        for (int i = 0; i < 4; ++i)
#pragma unroll
            for (int j = 0; j < 4; ++j)
                acc[i][j] = mfma16(af[i], bf[j], acc[i][j]);
        BAR();
    }

    // epilogue: D col=lane&15, row=(lane>>4)*4+reg
#pragma unroll
    for (int jf = 0; jf < 4; ++jf) {
        const int col = n0 + wc * 64 + jf * 16 + l15;
        const float bb = bias[col];
        if (QKV) {
            const int sect = col / 768;
            const int rem  = col - sect * 768;
            const int hh_  = rem >> 6, d = rem & 63;
#pragma unroll
            for (int i = 0; i < 4; ++i) {
                const int rowb = m0 + wr * 64 + i * 16 + l4 * 4;
                const size_t bh = (size_t)(rowb >> 11) * 12 + hh_;
                const int s0 = rowb & 2047;
                if (sect == 2) {
                    uv4 pk;
#pragma unroll
                    for (int reg = 0; reg < 4; ++reg) pk[reg] = f2bf(acc[i][jf][reg] + bb);
                    *(uv4*)&VTb[(bh * 64 + d) * 2048 + s0] = pk;
                } else if (sect == 0) {
#pragma unroll
                    for (int reg = 0; reg < 4; ++reg)
                        Qb[(bh * 2048 + s0 + reg) * 64 + d] =
                            f2bf((acc[i][jf][reg] + bb) * QSCALE);
                } else {
#pragma unroll
                    for (int reg = 0; reg < 4; ++reg)
                        Kb[(bh * 2048 + s0 + reg) * 64 + d] = f2bf(acc[i][jf][reg] + bb);
                }
            }
        } else {
#pragma unroll
            for (int i = 0; i < 4; ++i) {
                const int rowb = m0 + wr * 64 + i * 16 + l4 * 4;
#pragma unroll
                for (int reg = 0; reg < 4; ++reg)
                    Cf[(size_t)(rowb + reg) * N + col] = acc[i][jf][reg] + bb;
            }
        }
    }
}

// ---------------------------------------------------------------------------
// Flash attention (causal), S^T-swapped MFMA, exp2-domain softmax with
// defer-max, atomic work-queue (heavy q-tiles first). 512 blocks x 4 waves.
// Tile j -> qt = 31 - j/24 (descending work), bh = j%24.
// ---------------------------------------------------------------------------
__global__ __launch_bounds__(256)
void flash_mfma(const unsigned short* __restrict__ Qb, const unsigned short* __restrict__ Kb,
                const unsigned short* __restrict__ VTb, unsigned short* __restrict__ outb,
                int* __restrict__ cnt)
{
    __shared__ unsigned short sK [2][64 * 64];
    __shared__ unsigned short sVT[2][64 * 64];
    __shared__ unsigned short sP [4][16 * 64];
    __shared__ int sj;

    const int t = threadIdx.x, w = t >> 6, lane = t & 63;
    const int l15 = lane & 15, l4 = lane >> 4;

    // staging constants (independent of tile)
    const int sr0 = w * 8 + (lane >> 3), sc0 = (lane & 7) ^ (sr0 & 7);
    const int sr1 = (w + 4) * 8 + (lane >> 3), sc1 = (lane & 7) ^ (sr1 & 7);

    for (;;) {
        if (t == 0) sj = atomicAdd(cnt, 1);
        __syncthreads();
        const int j = sj;
        if (j >= NTILE) return;
        const int qt = 31 - j / 24;
        const int bh = j - (j / 24) * 24;
        const int b = bh / 12, h = bh - b * 12;
        const int qrow = qt * 64 + w * 16;

        const unsigned short* Kbase = Kb  + (size_t)bh * 2048 * 64;
        const unsigned short* Vbase = VTb + (size_t)bh * 64 * 2048;

        // Q as B-fragment: col=q=l15, k=d (pre-scaled by QSCALE in GEMM)
        bv8 qf[2];
        {
            const unsigned short* qp = Qb + ((size_t)bh * 2048 + qrow + l15) * 64 + l4 * 8;
            qf[0] = *(const bv8*)qp;
            qf[1] = *(const bv8*)(qp + 32);
        }

        fv4 o[4];
#pragma unroll
        for (int jf = 0; jf < 4; ++jf) o[jf] = fv4{0.f, 0.f, 0.f, 0.f};
        float m_ = -1e30f, l_ = 0.f;

        // prologue stage
        GLOAD_LDS16(Kbase + (size_t)sr0 * 64 + sc0 * 8, &sK[0][w * 512]);
        GLOAD_LDS16(Kbase + (size_t)sr1 * 64 + sc1 * 8, &sK[0][(w + 4) * 512]);
        GLOAD_LDS16(Vbase + (size_t)sr0 * 2048 + sc0 * 8, &sVT[0][w * 512]);
        GLOAD_LDS16(Vbase + (size_t)sr1 * 2048 + sc1 * 8, &sVT[0][(w + 4) * 512]);

        for (int kt = 0; kt <= qt; ++kt) {
            const int cur = kt & 1;
            if (kt < qt) {
                const int nk = kt + 1;
                GLOAD_LDS16(Kbase + (size_t)(nk * 64 + sr0) * 64 + sc0 * 8, &sK[cur ^ 1][w * 512]);
                GLOAD_LDS16(Kbase + (size_t)(nk * 64 + sr1) * 64 + sc1 * 8, &sK[cur ^ 1][(w + 4) * 512]);
                GLOAD_LDS16(Vbase + (size_t)sr0 * 2048 + nk * 64 + sc0 * 8, &sVT[cur ^ 1][w * 512]);
                GLOAD_LDS16(Vbase + (size_t)sr1 * 2048 + nk * 64 + sc1 * 8, &sVT[cur ^ 1][(w + 4) * 512]);
                VMCNT4();
            } else VMCNT0();
            BAR();

            // ---- S^T[kv][q] = K · Q ----
            fv4 st[4];
            __builtin_amdgcn_s_setprio(1);
#pragma unroll
            for (int jf = 0; jf < 4; ++jf) {
                st[jf] = fv4{0.f, 0.f, 0.f, 0.f};
                const int kr = jf * 16 + l15;
#pragma unroll
                for (int hh = 0; hh < 2; ++hh) {
                    const bv8 ka = *(const bv8*)&sK[cur][kr * 64 + (((hh * 4 + l4) ^ (kr & 7)) * 8)];
                    st[jf] = mfma16(ka, qf[hh], st[jf]);
                }
            }
            __builtin_amdgcn_s_setprio(0);

            // ---- mask (diag tile only); values already in log2 units ----
            float ps[16];
            const int qg = qrow + l15;
            if (kt == qt) {
#pragma unroll
                for (int jf = 0; jf < 4; ++jf)
#pragma unroll
                    for (int reg = 0; reg < 4; ++reg) {
                        const int kvg = kt * 64 + jf * 16 + l4 * 4 + reg;
                        ps[jf * 4 + reg] = (kvg > qg) ? MASKB : st[jf][reg];
                    }
            } else {
#pragma unroll
                for (int jf = 0; jf < 4; ++jf)
#pragma unroll
                    for (int reg = 0; reg < 4; ++reg) ps[jf * 4 + reg] = st[jf][reg];
            }

            // ---- online softmax, defer-max ----
            float rmax = ps[0];
#pragma unroll
            for (int u = 1; u < 16; ++u) rmax = fmaxf(rmax, ps[u]);
            rmax = fmaxf(rmax, __shfl_xor(rmax, 16));
            rmax = fmaxf(rmax, __shfl_xor(rmax, 32));
            if (!__all(rmax <= m_ + DEFER_THR)) {
                const float nm = fmaxf(m_, rmax);
                const float sc = exp2f(m_ - nm);
                float scq[4];
#pragma unroll
                for (int reg = 0; reg < 4; ++reg) scq[reg] = __shfl(sc, l4 * 4 + reg);
#pragma unroll
                for (int jf = 0; jf < 4; ++jf)
#pragma unroll
                    for (int reg = 0; reg < 4; ++reg) o[jf][reg] *= scq[reg];
                l_ *= sc;
                m_ = nm;
            }
            float psum = 0.f;
#pragma unroll
            for (int u = 0; u < 16; ++u) {
                const float p = exp2f(ps[u] - m_);
                ps[u] = p;
                psum += p;
            }
            psum += __shfl_xor(psum, 16);
            psum += __shfl_xor(psum, 32);
            l_ += psum;

            // ---- P -> LDS (packed b64, swizzled, own-wave region) ----
#pragma unroll
            for (int jf = 0; jf < 4; ++jf) {
                uv4 pk;
#pragma unroll
                for (int reg = 0; reg < 4; ++reg) pk[reg] = f2bf(ps[jf * 4 + reg]);
                const int chunk = jf * 2 + (l4 >> 1);
                *(uv4*)&sP[w][l15 * 64 + ((chunk ^ (l15 & 7)) * 8) + (l4 & 1) * 4] = pk;
            }

            // ---- O += P V ----
            bv8 pa[2];
#pragma unroll
            for (int hh = 0; hh < 2; ++hh)
                pa[hh] = *(const bv8*)&sP[w][l15 * 64 + (((hh * 4 + l4) ^ (l15 & 7)) * 8)];
            __builtin_amdgcn_s_setprio(1);
#pragma unroll
            for (int jf = 0; jf < 4; ++jf) {
                const int dr = jf * 16 + l15;
#pragma unroll
                for (int hh = 0; hh < 2; ++hh) {
                    const bv8 vb = *(const bv8*)&sVT[cur][dr * 64 + (((hh * 4 + l4) ^ (dr & 7)) * 8)];
                    o[jf] = mfma16(pa[hh], vb, o[jf]);
                }
            }
            __builtin_amdgcn_s_setprio(0);
            BAR();
        }

        // ---- epilogue ----
        const float inv = 1.0f / l_;
        float invq[4];
#pragma unroll
        for (int reg = 0; reg < 4; ++reg) invq[reg] = __shfl(inv, l4 * 4 + reg);
#pragma unroll
        for (int jf = 0; jf < 4; ++jf)
#pragma unroll
            for (int reg = 0; reg < 4; ++reg)
                outb[(size_t)(b * S_ + qrow + l4 * 4 + reg) * D_ + h * 64 + jf * 16 + l15] =
                    f2bf(o[jf][reg] * invq[reg]);
    }
}

// ---------------------------------------------------------------------------
extern "C" void kernel_launch(void* const* d_in, const int* in_sizes, int n_in,
                              void* d_out, int out_size, void* d_ws, size_t ws_size,
                              hipStream_t stream)
{
    const float* hs    = (const float*)d_in[0];
    const float* wqkv  = (const float*)d_in[1];
    const float* bqkv  = (const float*)d_in[2];
    const float* wproj = (const float*)d_in[3];
    const float* bproj = (const float*)d_in[4];
    float* out = (float*)d_out;

    unsigned short* hsb    = (unsigned short*)d_ws;                 // [4096][768]
    unsigned short* wqkvT  = hsb    + (size_t)M_ * D_;              // [2304][768]
    unsigned short* wprojT = wqkvT  + (size_t)N3D * D_;             // [768][768]
    unsigned short* Qb     = wprojT + (size_t)D_ * D_;              // [24][2048][64]
    unsigned short* Kb     = Qb     + (size_t)24 * 2048 * 64;
    unsigned short* VTb    = Kb     + (size_t)24 * 2048 * 64;       // [24][64][2048]
    unsigned short* attnb  = VTb    + (size_t)24 * 2048 * 64;       // [4096][768]
    int* cnt = (int*)(attnb + (size_t)M_ * D_);                     // queue counter

    cvt_f32_bf16<<<(M_ * D_) / (256 * 8), 256, 0, stream>>>(hs, hsb, cnt);
    transpose_cvt<<<dim3(N3D / 32, D_ / 32), 256, 0, stream>>>(wqkv, wqkvT, D_, N3D);
    transpose_cvt<<<dim3(D_ / 32, D_ / 32), 256, 0, stream>>>(wproj, wprojT, D_, D_);

    gemm_bf16<true><<<dim3(N3D / 128, M_ / 128), 256, 0, stream>>>(
        hsb, wqkvT, bqkv, nullptr, Qb, Kb, VTb, M_, N3D, D_);
    flash_mfma<<<512, 256, 0, stream>>>(Qb, Kb, VTb, attnb, cnt);
    gemm_bf16<false><<<dim3(D_ / 128, M_ / 128), 256, 0, stream>>>(
        attnb, wprojT, bproj, out, nullptr, nullptr, nullptr, M_, D_, D_);
}

// Round 5
// 170.856 us; speedup vs baseline: 5.7316x; 1.0398x over previous
//
#include <hip/hip_runtime.h>
#include <stdint.h>

// GPT-2 attention block, bf16 MFMA. Round 5:
//  - flash: fixed-m exp2 softmax (m folded into MFMA acc init), per-lane l,
//    no per-tile reduces/rescales; work-queue (heavy tiles first); dbuf+vmcnt.
//  - QKV GEMM: coalesced Q/K epilogue via reused LDS (swizzled repack).
//  - prep: single fused kernel (cvt + 2 weight transposes + queue reset).

constexpr int B_  = 2;
constexpr int S_  = 2048;
constexpr int D_  = 768;
constexpr int N3D = 3 * D_;   // 2304
constexpr int M_  = B_ * S_;  // 4096
constexpr int NTILE = 32 * 24;
// Q pre-scale: 1/sqrt(64) * log2(e); softmax in exp2 domain with FIXED m=8:
// exp2(logit - 8) -- the -8 is folded into the MFMA accumulator init.
#define QSCALE 0.1803368801111f
#define FIXED_M 8.0f

typedef __bf16 bv8 __attribute__((ext_vector_type(8)));
typedef float  fv4 __attribute__((ext_vector_type(4)));
typedef unsigned short uv4 __attribute__((ext_vector_type(4)));
typedef unsigned short uv8 __attribute__((ext_vector_type(8)));

__device__ inline unsigned short f2bf(float x) {
    __bf16 b = (__bf16)x;
    return __builtin_bit_cast(unsigned short, b);
}

__device__ inline fv4 mfma16(bv8 a, bv8 b, fv4 c) {
    return __builtin_amdgcn_mfma_f32_16x16x32_bf16(a, b, c, 0, 0, 0);
}

#define GLOAD_LDS16(g, l)                                                        \
    __builtin_amdgcn_global_load_lds(                                            \
        (__attribute__((address_space(1))) void*)(g),                            \
        (__attribute__((address_space(3))) void*)(l), 16, 0, 0)

#define VMCNT4() asm volatile("s_waitcnt vmcnt(4)" ::: "memory")
#define VMCNT0() asm volatile("s_waitcnt vmcnt(0)" ::: "memory")
#define BAR()                                                                    \
    do { asm volatile("" ::: "memory"); __builtin_amdgcn_s_barrier();            \
         asm volatile("" ::: "memory"); } while (0)

// ---------------------------------------------------------------------------
// Fused prep: [0,1536) cvt hs->bf16 ; [1536,3264) wqkv^T ; [3264,3840) wproj^T
// Block 0 also resets the flash work-queue counter.
// ---------------------------------------------------------------------------
__global__ __launch_bounds__(256)
void prep(const float* __restrict__ hs, const float* __restrict__ wqkv,
          const float* __restrict__ wproj, unsigned short* __restrict__ hsb,
          unsigned short* __restrict__ wqkvT, unsigned short* __restrict__ wprojT,
          int* __restrict__ cnt)
{
    __shared__ float tl[32][33];
    const int bid = blockIdx.x, t = threadIdx.x;
    if (bid == 0 && t == 0) *cnt = 0;

    if (bid < 1536) {
        const size_t i = ((size_t)bid * 256 + t) * 8;
        const float4 a = *(const float4*)&hs[i];
        const float4 b = *(const float4*)&hs[i + 4];
        uv8 o;
        o[0] = f2bf(a.x); o[1] = f2bf(a.y); o[2] = f2bf(a.z); o[3] = f2bf(a.w);
        o[4] = f2bf(b.x); o[5] = f2bf(b.y); o[6] = f2bf(b.z); o[7] = f2bf(b.w);
        *(uv8*)&hsb[i] = o;
        return;
    }

    const float* W;
    unsigned short* WT;
    int K, N, bx, by;
    if (bid < 3264) {
        W = wqkv; WT = wqkvT; K = 768; N = 2304;
        const int b2 = bid - 1536; bx = b2 % 72; by = b2 / 72;
    } else {
        W = wproj; WT = wprojT; K = 768; N = 768;
        const int b2 = bid - 3264; bx = b2 % 24; by = b2 / 24;
    }
    const int n0 = bx * 32, k0 = by * 32;
    {
        const int r = t >> 3, c = (t & 7) * 4;
        const float4 v = *(const float4*)&W[(size_t)(k0 + r) * N + n0 + c];
        tl[r][c + 0] = v.x; tl[r][c + 1] = v.y; tl[r][c + 2] = v.z; tl[r][c + 3] = v.w;
    }
    __syncthreads();
    {
        const int rn = t >> 3, ck = (t & 7) * 4;
        uv4 o;
        o[0] = f2bf(tl[ck + 0][rn]); o[1] = f2bf(tl[ck + 1][rn]);
        o[2] = f2bf(tl[ck + 2][rn]); o[3] = f2bf(tl[ck + 3][rn]);
        *(uv4*)&WT[(size_t)(n0 + rn) * K + k0 + ck] = o;
    }
}

// ---------------------------------------------------------------------------
// bf16 MFMA GEMM, 128x128 tile, BK=32, dbuf LDS, counted vmcnt.
// QKV=true : Q (x QSCALE) and K sections repack through reused LDS for
//            coalesced b128 stores; V^T section keeps b64 scatter.
// QKV=false: fp32 row-major C.
// ---------------------------------------------------------------------------
template<bool QKV>
__global__ __launch_bounds__(256)
void gemm_bf16(const unsigned short* __restrict__ A, const unsigned short* __restrict__ BT,
               const float* __restrict__ bias, float* __restrict__ Cf,
               unsigned short* __restrict__ Qb, unsigned short* __restrict__ Kb,
               unsigned short* __restrict__ VTb, int M, int N, int K)
{
    __shared__ unsigned short smem[16384];   // sA[2]|sB[2] during loop; T after
    unsigned short* const sA0 = smem;
    unsigned short* const sB0 = smem + 8192;

    const int t = threadIdx.x, w = t >> 6, lane = t & 63;
    const int l15 = lane & 15, l4 = lane >> 4;
    const int m0 = blockIdx.y * 128, n0 = blockIdx.x * 128;
    const int wr = w >> 1, wc = w & 1;

    fv4 acc[4][4];
#pragma unroll
    for (int i = 0; i < 4; ++i)
#pragma unroll
        for (int j = 0; j < 4; ++j) acc[i][j] = fv4{0.f, 0.f, 0.f, 0.f};

    const int r0 = w * 16 + (lane >> 2);
    const int c0 = (lane & 3) ^ ((r0 >> 1) & 3);
    const int r1 = (w + 4) * 16 + (lane >> 2);
    const int c1 = (lane & 3) ^ ((r1 >> 1) & 3);

    auto stage = [&](int buf, int k0) {
        GLOAD_LDS16(A  + (size_t)(m0 + r0) * K + k0 + c0 * 8, sA0 + buf * 4096 + w * 512);
        GLOAD_LDS16(A  + (size_t)(m0 + r1) * K + k0 + c1 * 8, sA0 + buf * 4096 + (w + 4) * 512);
        GLOAD_LDS16(BT + (size_t)(n0 + r0) * K + k0 + c0 * 8, sB0 + buf * 4096 + w * 512);
        GLOAD_LDS16(BT + (size_t)(n0 + r1) * K + k0 + c1 * 8, sB0 + buf * 4096 + (w + 4) * 512);
    };

    stage(0, 0);
    const int nt = K >> 5;
    for (int tt = 0; tt < nt; ++tt) {
        const int cur = tt & 1;
        if (tt + 1 < nt) { stage(cur ^ 1, (tt + 1) * 32); VMCNT4(); }
        else             { VMCNT0(); }
        BAR();

        bv8 af[4], bf[4];
#pragma unroll
        for (int i = 0; i < 4; ++i) {
            const int r = wr * 64 + i * 16 + l15;
            const int c = l4 ^ ((r >> 1) & 3);
            af[i] = *(const bv8*)&sA0[cur * 4096 + r * 32 + c * 8];
        }
#pragma unroll
        for (int j = 0; j < 4; ++j) {
            const int r = wc * 64 + j * 16 + l15;
            const int c = l4 ^ ((r >> 1) & 3);
            bf[j] = *(const bv8*)&sB0[cur * 4096 + r * 32 + c * 8];
        }
        __builtin_amdgcn_s_setprio(1);
#pragma unroll
        for (int i = 0; i < 4; ++i)
#pragma unroll
            for (int j = 0; j < 4; ++j)
                acc[i][j] = mfma16(af[i], bf[j], acc[i][j]);
        __builtin_amdgcn_s_setprio(0);
        BAR();
    }

    if (QKV) {
        const int sect = n0 / 768;           // uniform per block (768%128==0)
        const int rem0 = n0 - sect * 768;
        if (sect < 2) {
            // ---- pass 1: acc -> T[128][128] bf16, chunk-XOR swizzled ----
            const float qs = (sect == 0) ? QSCALE : 1.0f;
#pragma unroll
            for (int jf = 0; jf < 4; ++jf) {
                const int c = wc * 64 + jf * 16 + l15;
                const float bb = bias[n0 + c];
                const int ch = c >> 3, off = c & 7;
#pragma unroll
                for (int i = 0; i < 4; ++i) {
                    const int rb = wr * 64 + i * 16 + l4 * 4;
#pragma unroll
                    for (int reg = 0; reg < 4; ++reg) {
                        const int r = rb + reg;
                        smem[r * 128 + ((ch ^ (r & 15)) << 3) + off] =
                            f2bf((acc[i][jf][reg] + bb) * qs);
                    }
                }
            }
            __syncthreads();
            // ---- pass 2: cooperative coalesced b128 stores ----
            unsigned short* const dstQK = (sect == 0) ? Qb : Kb;
            const int brow = m0 >> 11, sbase = m0 & 2047, hb = rem0 >> 6;
#pragma unroll
            for (int u = 0; u < 8; ++u) {
                const int ID = t + 256 * u;
                const int s = ID >> 4, ch = ID & 15;      // ch = hh*8+dc
                const int hh = ch >> 3, dc = ch & 7;
                const uv8 v = *(const uv8*)&smem[s * 128 + ((ch ^ (s & 15)) << 3)];
                const size_t bh = (size_t)brow * 12 + hb + hh;
                *(uv8*)&dstQK[(bh * 2048 + sbase + s) * 64 + dc * 8] = v;
            }
        } else {
            // ---- V section: direct V^T b64 scatter ----
#pragma unroll
            for (int jf = 0; jf < 4; ++jf) {
                const int col = n0 + wc * 64 + jf * 16 + l15;
                const float bb = bias[col];
                const int rem = col - 2 * 768;
                const int hh_ = rem >> 6, d = rem & 63;
#pragma unroll
                for (int i = 0; i < 4; ++i) {
                    const int rowb = m0 + wr * 64 + i * 16 + l4 * 4;
                    const size_t bh = (size_t)(rowb >> 11) * 12 + hh_;
                    const int s0 = rowb & 2047;
                    uv4 pk;
#pragma unroll
                    for (int reg = 0; reg < 4; ++reg) pk[reg] = f2bf(acc[i][jf][reg] + bb);
                    *(uv4*)&VTb[(bh * 64 + d) * 2048 + s0] = pk;
                }
            }
        }
    } else {
#pragma unroll
        for (int jf = 0; jf < 4; ++jf) {
            const int col = n0 + wc * 64 + jf * 16 + l15;
            const float bb = bias[col];
#pragma unroll
            for (int i = 0; i < 4; ++i) {
                const int rowb = m0 + wr * 64 + i * 16 + l4 * 4;
#pragma unroll
                for (int reg = 0; reg < 4; ++reg)
                    Cf[(size_t)(rowb + reg) * N + col] = acc[i][jf][reg] + bb;
            }
        }
    }
}

// ---------------------------------------------------------------------------
// Flash attention (causal), S^T-swapped MFMA, FIXED-m exp2 softmax.
// P = exp2(logit - 8) (the -8 is the MFMA acc init); exact after the final
// division by l. No max tracking, no rescale, per-lane l partial sums.
// Atomic work-queue, 512 persistent blocks, heavy q-tiles first.
// ---------------------------------------------------------------------------
__global__ __launch_bounds__(256)
void flash_mfma(const unsigned short* __restrict__ Qb, const unsigned short* __restrict__ Kb,
                const unsigned short* __restrict__ VTb, unsigned short* __restrict__ outb,
                int* __restrict__ cnt)
{
    __shared__ unsigned short sK [2][64 * 64];
    __shared__ unsigned short sVT[2][64 * 64];
    __shared__ unsigned short sP [4][16 * 64];
    __shared__ int sj;

    const int t = threadIdx.x, w = t >> 6, lane = t & 63;
    const int l15 = lane & 15, l4 = lane >> 4;

    const int sr0 = w * 8 + (lane >> 3), sc0 = (lane & 7) ^ (sr0 & 7);
    const int sr1 = (w + 4) * 8 + (lane >> 3), sc1 = (lane & 7) ^ (sr1 & 7);

    for (;;) {
        if (t == 0) sj = atomicAdd(cnt, 1);
        __syncthreads();
        const int j = sj;
        if (j >= NTILE) return;
        const int qt = 31 - j / 24;
        const int bh = j - (j / 24) * 24;
        const int b = bh / 12, h = bh - b * 12;
        const int qrow = qt * 64 + w * 16;

        const unsigned short* Kbase = Kb  + (size_t)bh * 2048 * 64;
        const unsigned short* Vbase = VTb + (size_t)bh * 64 * 2048;

        bv8 qf[2];
        {
            const unsigned short* qp = Qb + ((size_t)bh * 2048 + qrow + l15) * 64 + l4 * 8;
            qf[0] = *(const bv8*)qp;
            qf[1] = *(const bv8*)(qp + 32);
        }

        fv4 o[4];
#pragma unroll
        for (int jf = 0; jf < 4; ++jf) o[jf] = fv4{0.f, 0.f, 0.f, 0.f};
        float l_ = 0.f;

        GLOAD_LDS16(Kbase + (size_t)sr0 * 64 + sc0 * 8, &sK[0][w * 512]);
        GLOAD_LDS16(Kbase + (size_t)sr1 * 64 + sc1 * 8, &sK[0][(w + 4) * 512]);
        GLOAD_LDS16(Vbase + (size_t)sr0 * 2048 + sc0 * 8, &sVT[0][w * 512]);
        GLOAD_LDS16(Vbase + (size_t)sr1 * 2048 + sc1 * 8, &sVT[0][(w + 4) * 512]);

        for (int kt = 0; kt <= qt; ++kt) {
            const int cur = kt & 1;
            if (kt < qt) {
                const int nk = kt + 1;
                GLOAD_LDS16(Kbase + (size_t)(nk * 64 + sr0) * 64 + sc0 * 8, &sK[cur ^ 1][w * 512]);
                GLOAD_LDS16(Kbase + (size_t)(nk * 64 + sr1) * 64 + sc1 * 8, &sK[cur ^ 1][(w + 4) * 512]);
                GLOAD_LDS16(Vbase + (size_t)sr0 * 2048 + nk * 64 + sc0 * 8, &sVT[cur ^ 1][w * 512]);
                GLOAD_LDS16(Vbase + (size_t)sr1 * 2048 + nk * 64 + sc1 * 8, &sVT[cur ^ 1][(w + 4) * 512]);
                VMCNT4();
            } else VMCNT0();
            BAR();

            // ---- S^T[kv][q] = K . Q  (acc init = -FIXED_M) ----
            fv4 st[4];
            __builtin_amdgcn_s_setprio(1);
#pragma unroll
            for (int jf = 0; jf < 4; ++jf) {
                st[jf] = fv4{-FIXED_M, -FIXED_M, -FIXED_M, -FIXED_M};
                const int kr = jf * 16 + l15;
#pragma unroll
                for (int hh = 0; hh < 2; ++hh) {
                    const bv8 ka = *(const bv8*)&sK[cur][kr * 64 + (((hh * 4 + l4) ^ (kr & 7)) * 8)];
                    st[jf] = mfma16(ka, qf[hh], st[jf]);
                }
            }
            __builtin_amdgcn_s_setprio(0);

            // ---- P = exp2(st), causal mask on diag tile; accumulate l ----
            float ps[16];
            const int qg = qrow + l15;
            if (kt == qt) {
#pragma unroll
                for (int jf = 0; jf < 4; ++jf)
#pragma unroll
                    for (int reg = 0; reg < 4; ++reg) {
                        const int kvg = kt * 64 + jf * 16 + l4 * 4 + reg;
                        ps[jf * 4 + reg] = (kvg > qg) ? -30000.f : st[jf][reg];
                    }
            } else {
#pragma unroll
                for (int jf = 0; jf < 4; ++jf)
#pragma unroll
                    for (int reg = 0; reg < 4; ++reg) ps[jf * 4 + reg] = st[jf][reg];
            }
#pragma unroll
            for (int u = 0; u < 16; ++u) {
                const float p = exp2f(ps[u]);
                ps[u] = p;
                l_ += p;
            }

            // ---- P -> LDS (packed b64, swizzled, own-wave region) ----
#pragma unroll
            for (int jf = 0; jf < 4; ++jf) {
                uv4 pk;
#pragma unroll
                for (int reg = 0; reg < 4; ++reg) pk[reg] = f2bf(ps[jf * 4 + reg]);
                const int chunk = jf * 2 + (l4 >> 1);
                *(uv4*)&sP[w][l15 * 64 + ((chunk ^ (l15 & 7)) * 8) + (l4 & 1) * 4] = pk;
            }

            // ---- O += P V ----
            bv8 pa[2];
#pragma unroll
            for (int hh = 0; hh < 2; ++hh)
                pa[hh] = *(const bv8*)&sP[w][l15 * 64 + (((hh * 4 + l4) ^ (l15 & 7)) * 8)];
            __builtin_amdgcn_s_setprio(1);
#pragma unroll
            for (int jf = 0; jf < 4; ++jf) {
                const int dr = jf * 16 + l15;
#pragma unroll
                for (int hh = 0; hh < 2; ++hh) {
                    const bv8 vb = *(const bv8*)&sVT[cur][dr * 64 + (((hh * 4 + l4) ^ (dr & 7)) * 8)];
                    o[jf] = mfma16(pa[hh], vb, o[jf]);
                }
            }
            __builtin_amdgcn_s_setprio(0);
            BAR();
        }

        // ---- epilogue: reduce l across l4 group, normalize, store ----
        l_ += __shfl_xor(l_, 16);
        l_ += __shfl_xor(l_, 32);
        const float inv = 1.0f / l_;
        float invq[4];
#pragma unroll
        for (int reg = 0; reg < 4; ++reg) invq[reg] = __shfl(inv, l4 * 4 + reg);
#pragma unroll
        for (int jf = 0; jf < 4; ++jf)
#pragma unroll
            for (int reg = 0; reg < 4; ++reg)
                outb[(size_t)(b * S_ + qrow + l4 * 4 + reg) * D_ + h * 64 + jf * 16 + l15] =
                    f2bf(o[jf][reg] * invq[reg]);
    }
}

// ---------------------------------------------------------------------------
extern "C" void kernel_launch(void* const* d_in, const int* in_sizes, int n_in,
                              void* d_out, int out_size, void* d_ws, size_t ws_size,
                              hipStream_t stream)
{
    const float* hs    = (const float*)d_in[0];
    const float* wqkv  = (const float*)d_in[1];
    const float* bqkv  = (const float*)d_in[2];
    const float* wproj = (const float*)d_in[3];
    const float* bproj = (const float*)d_in[4];
    float* out = (float*)d_out;

    unsigned short* hsb    = (unsigned short*)d_ws;                 // [4096][768]
    unsigned short* wqkvT  = hsb    + (size_t)M_ * D_;              // [2304][768]
    unsigned short* wprojT = wqkvT  + (size_t)N3D * D_;             // [768][768]
    unsigned short* Qb     = wprojT + (size_t)D_ * D_;              // [24][2048][64]
    unsigned short* Kb     = Qb     + (size_t)24 * 2048 * 64;
    unsigned short* VTb    = Kb     + (size_t)24 * 2048 * 64;       // [24][64][2048]
    unsigned short* attnb  = VTb    + (size_t)24 * 2048 * 64;       // [4096][768]
    int* cnt = (int*)(attnb + (size_t)M_ * D_);

    prep<<<3840, 256, 0, stream>>>(hs, wqkv, wproj, hsb, wqkvT, wprojT, cnt);
    gemm_bf16<true><<<dim3(N3D / 128, M_ / 128), 256, 0, stream>>>(
        hsb, wqkvT, bqkv, nullptr, Qb, Kb, VTb, M_, N3D, D_);
    flash_mfma<<<512, 256, 0, stream>>>(Qb, Kb, VTb, attnb, cnt);
    gemm_bf16<false><<<dim3(D_ / 128, M_ / 128), 256, 0, stream>>>(
        attnb, wprojT, bproj, out, nullptr, nullptr, nullptr, M_, D_, D_);
}